// Round 5
// baseline (501.474 us; speedup 1.0000x reference)
//
#include <hip/hip_runtime.h>
#include <hip/hip_bf16.h>

// LocalGNN forward, 4-kernel fused pipeline.
// h_{p+1} = D (G+I) D h_p  computed as  acc = (G+I)bf16 @ (d_j h_p,j)bf16, h=d_i*acc.
// K0: G fp32 -> rowsum(dinv) + (G+I) bf16 A-frag swizzle + x B-frags + W frags.
//     (LDS-free: each lane loads exactly its A-frag bytes contiguously.)
// K1/K2: prop pass -> hrow_p (bf16 row-major) + hF_p (d-scaled B-frags).
// K3: prop pass 3 + fused [x,h1,h2,h3] @ W^T + bias epilogue.
// B=4, N=4096, DIM=64. fp32 in/out, bf16 MFMA internally (2% rel tol).

typedef __attribute__((ext_vector_type(4))) float  floatx4;
typedef __attribute__((ext_vector_type(8))) short  short8;

#define NB 4
#define NN 4096
#define ND 64
#define HF_B 262144   // shorts per batch in hF: 128 kc * 4 c * 64 ln * 8

__device__ __forceinline__ unsigned short f2bf_bits(float v) {
    __hip_bfloat16 b = __float2bfloat16(v);
    return *reinterpret_cast<unsigned short*>(&b);
}
__device__ __forceinline__ float bf2f(unsigned short u) {
    unsigned int x = ((unsigned int)u) << 16;
    return *reinterpret_cast<float*>(&x);
}
__device__ __forceinline__ short8 pack8p(const float* v) {
    short8 r;
#pragma unroll
    for (int j = 0; j < 8; ++j) r[j] = (short)f2bf_bits(v[j]);
    return r;
}

// ================================================================ K0
// block = tile tt = (b, mt): 16 rows x 4096 cols of G. LDS-free hot loop:
// lane ln=(q*16+m) of wave w loads G[mt*16+m][kc*32+q*8..+8] (32 B contig),
// rowsum in registers, +I by compare, pack bf16, coalesced 1-KB store/wave.
__global__ __launch_bounds__(256) void prep_graph(const float* __restrict__ g,
                                                  const float* __restrict__ x,
                                                  const float* __restrict__ W,
                                                  float* __restrict__ dinv,
                                                  unsigned short* __restrict__ gswz,
                                                  unsigned short* __restrict__ hF0,
                                                  unsigned short* __restrict__ Wf) {
    __shared__ float wsum[4][16];
    __shared__ float dl[16];
    int tt = blockIdx.x;                 // 0..1023
    int b = tt >> 8, mt = tt & 255;
    int t = threadIdx.x;
    int w = t >> 6, ln = t & 63;
    int m = ln & 15, q = ln >> 4;
    int i_row = mt * 16 + m;
    const float* grow = g + (((size_t)b * NN + i_row) * NN);
    unsigned short* gout = gswz + (size_t)tt * 128 * 512 + (size_t)(w * 32) * 512 + ln * 8;
    float rs = 0.f;

#pragma unroll 4
    for (int kk = 0; kk < 32; ++kk) {
        int kc = w * 32 + kk;
        int col = kc * 32 + q * 8;
        floatx4 v0 = *reinterpret_cast<const floatx4*>(grow + col);
        floatx4 v1 = *reinterpret_cast<const floatx4*>(grow + col + 4);
        rs += v0[0] + v0[1] + v0[2] + v0[3] + v1[0] + v1[1] + v1[2] + v1[3];
        float v[8] = {v0[0], v0[1], v0[2], v0[3], v1[0], v1[1], v1[2], v1[3]};
        if (i_row >= col && i_row < col + 8) v[i_row - col] += 1.0f;   // +I
        *reinterpret_cast<short8*>(gout + (size_t)kk * 512) = pack8p(v);
    }
    // rowsum: fold q-groups (lane^16, lane^32), then combine 4 waves via LDS
    rs += __shfl_xor(rs, 16);
    rs += __shfl_xor(rs, 32);
    if (q == 0) wsum[w][m] = rs;
    __syncthreads();
    if (t < 16) {
        float tot = wsum[0][t] + wsum[1][t] + wsum[2][t] + wsum[3][t] + 1.0f;
        float d = 1.0f / (sqrtf(tot) + 1e-7f);
        dinv[b * NN + mt * 16 + t] = d;
        dl[t] = d;
    }
    __syncthreads();
    // hF0 = d_j * x_j for this tile's 16 rows (half-window kc=mt>>1, parity mt&1)
    if (t < 128) {
        int c = t >> 5, lnl = t & 31;
        int q_loc = lnl >> 4, mm = lnl & 15;
        int u = mt & 1;
        int lno = u * 32 + lnl;
        int kc2 = mt >> 1;
        float v[8];
#pragma unroll
        for (int j = 0; j < 8; ++j) {
            int lr = q_loc * 8 + j;                      // 0..15
            v[j] = dl[lr] * x[((size_t)b * NN + mt * 16 + lr) * ND + c * 16 + mm];
        }
        *reinterpret_cast<short8*>(hF0 + (size_t)b * HF_B + ((size_t)(kc2 * 4 + c) * 64 + lno) * 8) = pack8p(v);
    }
    // W -> B-frag layout (block 0 only)
    if (tt == 0) {
#pragma unroll
        for (int e = 0; e < 8; ++e) {
            int wi = e * 256 + t;                        // 0..2047
            int kc = wi >> 8;
            int c = (wi >> 6) & 3;
            int lno = wi & 63;
            int mm = lno & 15, qq = lno >> 4;
            float v[8];
#pragma unroll
            for (int j = 0; j < 8; ++j) v[j] = W[(size_t)(c * 16 + mm) * 256 + kc * 32 + qq * 8 + j];
            *reinterpret_cast<short8*>(Wf + ((size_t)(kc * 4 + c) * 64 + lno) * 8) = pack8p(v);
        }
    }
}

// ================================================================ prop core
#define PROP_MAIN()                                                                      \
    int bid = blockIdx.x;                                                                \
    int b = bid >> 7, mk = bid & 127;                                                    \
    int t = threadIdx.x;                                                                 \
    int w = t >> 6, lane = t & 63;                                                       \
    int m = lane & 15, q = lane >> 4;                                                    \
    int tt0 = b * 256 + mk * 2;                                                          \
    const unsigned short* Ap0 = gswz + ((size_t)tt0 * 128 + w * 32) * 512 + lane * 8;    \
    const unsigned short* Ap1 = Ap0 + (size_t)128 * 512;                                 \
    const unsigned short* Bp  = hFin + (size_t)b * HF_B + (size_t)(w * 32) * 2048 + lane * 8; \
    floatx4 acc0[4], acc1[4];                                                            \
    _Pragma("unroll")                                                                    \
    for (int c = 0; c < 4; ++c) { acc0[c] = (floatx4){0.f,0.f,0.f,0.f}; acc1[c] = acc0[c]; } \
    _Pragma("unroll 2")                                                                  \
    for (int kc = 0; kc < 32; ++kc) {                                                    \
        short8 a0 = *reinterpret_cast<const short8*>(Ap0);                               \
        short8 a1 = *reinterpret_cast<const short8*>(Ap1);                               \
        short8 b0 = *reinterpret_cast<const short8*>(Bp);                                \
        short8 b1 = *reinterpret_cast<const short8*>(Bp + 512);                          \
        short8 b2 = *reinterpret_cast<const short8*>(Bp + 1024);                         \
        short8 b3 = *reinterpret_cast<const short8*>(Bp + 1536);                         \
        Ap0 += 512; Ap1 += 512; Bp += 2048;                                              \
        acc0[0] = __builtin_amdgcn_mfma_f32_16x16x32_bf16(a0, b0, acc0[0], 0, 0, 0);     \
        acc1[0] = __builtin_amdgcn_mfma_f32_16x16x32_bf16(a1, b0, acc1[0], 0, 0, 0);     \
        acc0[1] = __builtin_amdgcn_mfma_f32_16x16x32_bf16(a0, b1, acc0[1], 0, 0, 0);     \
        acc1[1] = __builtin_amdgcn_mfma_f32_16x16x32_bf16(a1, b1, acc1[1], 0, 0, 0);     \
        acc0[2] = __builtin_amdgcn_mfma_f32_16x16x32_bf16(a0, b2, acc0[2], 0, 0, 0);     \
        acc1[2] = __builtin_amdgcn_mfma_f32_16x16x32_bf16(a1, b2, acc1[2], 0, 0, 0);     \
        acc0[3] = __builtin_amdgcn_mfma_f32_16x16x32_bf16(a0, b3, acc0[3], 0, 0, 0);     \
        acc1[3] = __builtin_amdgcn_mfma_f32_16x16x32_bf16(a1, b3, acc1[3], 0, 0, 0);     \
    }                                                                                    \
    if (t < 32) dl[t] = dinv[b * NN + mk * 32 + t];                                      \
    for (int u = 0; u < 2; ++u) {                                                        \
        __syncthreads();                                                                 \
        floatx4* acc = u ? acc1 : acc0;                                                  \
        _Pragma("unroll")                                                                \
        for (int c = 0; c < 4; ++c)                                                      \
            _Pragma("unroll")                                                            \
            for (int r = 0; r < 4; ++r) buf[w][q * 4 + r][c * 16 + m] = acc[c][r];       \
        __syncthreads();                                                                 \
        _Pragma("unroll")                                                                \
        for (int e = 0; e < 4; ++e) {                                                    \
            int idx = e * 256 + t;                                                       \
            int r = idx >> 6, col = idx & 63;                                            \
            float s = buf[0][r][col] + buf[1][r][col] + buf[2][r][col] + buf[3][r][col]; \
            int lr = u * 16 + r;                                                         \
            hsh[lr][col] = f2bf_bits(dl[lr] * s);                                        \
        }                                                                                \
    }                                                                                    \
    __syncthreads();

// K1/K2: emit hrow_p + hF_p
__global__ __launch_bounds__(256) void prop_pass(const unsigned short* __restrict__ gswz,
                                                 const unsigned short* __restrict__ hFin,
                                                 const float* __restrict__ dinv,
                                                 unsigned short* __restrict__ hrow,
                                                 unsigned short* __restrict__ hFout) {
    __shared__ float buf[4][16][68];
    __shared__ unsigned short hsh[32][64];
    __shared__ float dl[32];
    PROP_MAIN()
    // hrow: coalesced bf16 store of 32x64
    {
        unsigned short* hp = hrow + ((size_t)b * NN + mk * 32) * ND;
#pragma unroll
        for (int e = 0; e < 8; ++e) {
            int idx = e * 256 + t;
            hp[idx] = hsh[idx >> 6][idx & 63];
        }
    }
    // hF: kc = mk, value = d_j * h_j
    {
        int c = t >> 6, ln = t & 63;
        int mm = ln & 15, qq = ln >> 4;
        float v[8];
#pragma unroll
        for (int j = 0; j < 8; ++j) {
            int lr = qq * 8 + j;                         // 0..31
            v[j] = dl[lr] * bf2f(hsh[lr][c * 16 + mm]);
        }
        *reinterpret_cast<short8*>(hFout + (size_t)b * HF_B + ((size_t)(mk * 4 + c) * 64 + ln) * 8) = pack8p(v);
    }
}

// K3: pass 3 + fused final linear: out = [x,h1,h2,h3] @ W^T + bias
__global__ __launch_bounds__(256) void prop_final(const unsigned short* __restrict__ gswz,
                                                  const unsigned short* __restrict__ hFin,
                                                  const float* __restrict__ dinv,
                                                  const float* __restrict__ x,
                                                  const unsigned short* __restrict__ hrow1,
                                                  const unsigned short* __restrict__ hrow2,
                                                  const unsigned short* __restrict__ Wf,
                                                  const float* __restrict__ bias,
                                                  float* __restrict__ out) {
    __shared__ float buf[4][16][68];
    __shared__ unsigned short hsh[32][64];
    __shared__ float dl[32];
    PROP_MAIN()
    // epilogue: waves 0,1 -> tiles u=0,1 (32 MFMA each)
    if (w < 2) {
        int u = w;
        int grow = b * NN + mk * 32 + u * 16 + m;        // A row for this lane
        floatx4 facc[4];
#pragma unroll
        for (int c = 0; c < 4; ++c) facc[c] = (floatx4){0.f, 0.f, 0.f, 0.f};
#pragma unroll
        for (int p = 0; p < 4; ++p) {
#pragma unroll
            for (int ki = 0; ki < 2; ++ki) {
                short8 af;
                if (p == 0) {
                    const float* xp = x + (size_t)grow * ND + ki * 32 + q * 8;
                    float v[8];
#pragma unroll
                    for (int j = 0; j < 8; ++j) v[j] = xp[j];
                    af = pack8p(v);
                } else if (p == 1) {
                    af = *reinterpret_cast<const short8*>(hrow1 + (size_t)grow * ND + ki * 32 + q * 8);
                } else if (p == 2) {
                    af = *reinterpret_cast<const short8*>(hrow2 + (size_t)grow * ND + ki * 32 + q * 8);
                } else {
                    af = *reinterpret_cast<const short8*>(&hsh[u * 16 + m][ki * 32 + q * 8]);
                }
                int kc = p * 2 + ki;
#pragma unroll
                for (int c = 0; c < 4; ++c) {
                    short8 bf = *reinterpret_cast<const short8*>(Wf + ((size_t)(kc * 4 + c) * 64 + lane) * 8);
                    facc[c] = __builtin_amdgcn_mfma_f32_16x16x32_bf16(af, bf, facc[c], 0, 0, 0);
                }
            }
        }
#pragma unroll
        for (int c = 0; c < 4; ++c) {
            float bb = bias[c * 16 + m];
#pragma unroll
            for (int r = 0; r < 4; ++r) {
                int row = b * NN + mk * 32 + u * 16 + q * 4 + r;
                out[(size_t)row * ND + c * 16 + m] = facc[c][r] + bb;
            }
        }
    }
}

// ================================================================ launch
extern "C" void kernel_launch(void* const* d_in, const int* in_sizes, int n_in,
                              void* d_out, int out_size, void* d_ws, size_t ws_size,
                              hipStream_t stream) {
    const float* x     = (const float*)d_in[0];
    const float* graph = (const float*)d_in[1];
    const float* W     = (const float*)d_in[2];
    const float* bias  = (const float*)d_in[3];
    float* out = (float*)d_out;

    // workspace layout (bytes)
    char* w = (char*)d_ws;
    float*          dinv  = (float*)w;                         //  64 KB
    unsigned short* Wf    = (unsigned short*)(w + (1 << 16));  //  16 KB
    unsigned short* hFa   = (unsigned short*)(w + (1 << 17));  //   2 MB
    unsigned short* hFb   = hFa + (size_t)NB * HF_B;           //   2 MB
    unsigned short* hrow1 = hFb + (size_t)NB * HF_B;           //   2 MB
    unsigned short* hrow2 = hrow1 + (size_t)NB * NN * ND;      //   2 MB
    unsigned short* gswz  = hrow2 + (size_t)NB * NN * ND;      // 134 MB

    prep_graph<<<1024, 256, 0, stream>>>(graph, x, W, dinv, gswz, hFa, Wf);
    prop_pass<<<512, 256, 0, stream>>>(gswz, hFa, dinv, hrow1, hFb);
    prop_pass<<<512, 256, 0, stream>>>(gswz, hFb, dinv, hrow2, hFa);
    prop_final<<<512, 256, 0, stream>>>(gswz, hFa, dinv, x, hrow1, hrow2, Wf, bias, out);
}